// Round 7
// baseline (190.246 us; speedup 1.0000x reference)
//
#include <hip/hip_runtime.h>

#define NROWS 8192
#define INCH 10
#define NQKV 33
#define OUTCH 11
#define SPLIT 16
#define KB 512            // k-rows per block (single LDS stage)
#define QBLK 128          // q-rows per block (4 waves x 32)

typedef short short8 __attribute__((ext_vector_type(8)));
typedef float f32x16 __attribute__((ext_vector_type(16)));
typedef unsigned int uvec4 __attribute__((ext_vector_type(4)));

// ws byte layout:
//   QB_OFF: Q bf16 [NROWS][16ch] rows of 32B (scale*log2e folded into q)
//   KB_OFF: K bf16 planes [2][NROWS][16B]: plane c holds ch 8c..8c+7
//   VT_OFF: V^T bf16 interleaved: 16B unit u=(k>>3)*16+d holds V[k8*8+slot][d],
//           d=0..10 v, d=11 ones (softmax denom), d=12..15 zero
//   PART_OFF: f32 [SPLIT][NROWS][12] per-k-chunk partials (o0..o10, l)
//   CNT_OFF: int [NROWS/QBLK] fan-in counters (zeroed by kernel A each launch)
#define QB_OFF   0
#define KB_OFF   (NROWS * 32)
#define VT_OFF   (2 * NROWS * 32)
#define PART_OFF (3 * NROWS * 32)
#define CNT_OFF  (PART_OFF + SPLIT * NROWS * 12 * 4)

// v_permlane32_swap_b32 a, b:
//   a' = {a.lo32lanes, b.lo32lanes}, b' = {a.hi32lanes, b.hi32lanes}
#define SWAP32(a, b) asm("v_permlane32_swap_b32 %0, %1" : "+v"(a), "+v"(b))

__device__ inline unsigned short f2bf(float f) {
  unsigned u = __float_as_uint(f);
  unsigned r = (u + 0x7FFFu + ((u >> 16) & 1u)) >> 16;  // RNE
  return (unsigned short)r;
}

// ---------------------------------------------------------------------------
// Kernel A: LayerNorm + Linear(10->33); emit bf16 Q rows, K planes, V^T.
// Also zeroes the fan-in counters (stream order guarantees visibility to B).
// ---------------------------------------------------------------------------
__global__ __launch_bounds__(64) void qkv_ln_kernel(
    const float* __restrict__ x, const float* __restrict__ gamma,
    const float* __restrict__ beta, const float* __restrict__ W,
    char* __restrict__ ws) {
  __shared__ float sW[NQKV * INCH];
  __shared__ float sg[INCH];
  __shared__ float sb[INCH];
  int tid = threadIdx.x;
  for (int i = tid; i < NQKV * INCH; i += 64) sW[i] = W[i];
  if (tid < INCH) { sg[tid] = gamma[tid]; sb[tid] = beta[tid]; }
  if (blockIdx.x == 0) ((int*)(ws + CNT_OFF))[tid] = 0;  // 64 counters
  __syncthreads();

  int row = blockIdx.x * 64 + tid;
  const float2* x2 = (const float2*)x;  // rows are 40B = 5 float2, 8B aligned
  float xv[INCH];
#pragma unroll
  for (int j = 0; j < 5; ++j) {
    float2 t = x2[row * 5 + j];
    xv[2 * j] = t.x;
    xv[2 * j + 1] = t.y;
  }

  float mu = 0.f;
#pragma unroll
  for (int i = 0; i < INCH; ++i) mu += xv[i];
  mu *= (1.0f / INCH);
  float var = 0.f;
#pragma unroll
  for (int i = 0; i < INCH; ++i) { float d = xv[i] - mu; var += d * d; }
  var *= (1.0f / INCH);
  float rstd = rsqrtf(var + 1e-5f);
  float h[INCH];
#pragma unroll
  for (int i = 0; i < INCH; ++i) h[i] = (xv[i] - mu) * rstd * sg[i] + sb[i];

  float acc[NQKV];
#pragma unroll
  for (int oc = 0; oc < NQKV; ++oc) {
    float s = 0.f;
#pragma unroll
    for (int i = 0; i < INCH; ++i) s += h[i] * sW[oc * INCH + i];
    acc[oc] = s;
  }

  // exp(s*scale) = exp2(s*scale*log2e): fold into q.
  const float QSC = 0.31622776601683794f * 1.4426950408889634f;

  unsigned short e[16];
  unsigned qw[8];
  // ---- Q row ----
#pragma unroll
  for (int i = 0; i < 16; ++i) e[i] = (i < OUTCH) ? f2bf(acc[i] * QSC) : 0;
#pragma unroll
  for (int i = 0; i < 8; ++i)
    qw[i] = (unsigned)e[2 * i] | ((unsigned)e[2 * i + 1] << 16);
  uint4* Qb = (uint4*)(ws + QB_OFF);
  Qb[row * 2 + 0] = make_uint4(qw[0], qw[1], qw[2], qw[3]);
  Qb[row * 2 + 1] = make_uint4(qw[4], qw[5], qw[6], qw[7]);
  // ---- K planes ----
#pragma unroll
  for (int i = 0; i < 16; ++i) e[i] = (i < OUTCH) ? f2bf(acc[OUTCH + i]) : 0;
#pragma unroll
  for (int i = 0; i < 8; ++i)
    qw[i] = (unsigned)e[2 * i] | ((unsigned)e[2 * i + 1] << 16);
  uint4* Kb = (uint4*)(ws + KB_OFF);
  Kb[row] = make_uint4(qw[0], qw[1], qw[2], qw[3]);          // plane 0
  Kb[NROWS + row] = make_uint4(qw[4], qw[5], qw[6], qw[7]);  // plane 1
  // ---- V^T scatter (2B stores into interleaved units) ----
  unsigned short* VTu = (unsigned short*)(ws + VT_OFF);
  int u0 = (row >> 3) * 16;
  int slot = row & 7;
#pragma unroll
  for (int d = 0; d < 16; ++d) {
    unsigned short v;
    if (d < OUTCH)       v = f2bf(acc[2 * OUTCH + d]);
    else if (d == OUTCH) v = 0x3F80;  // ones column -> softmax denominator
    else                 v = 0;
    VTu[(u0 + d) * 8 + slot] = v;
  }
}

// ---------------------------------------------------------------------------
// Kernel B: MFMA flash attention partial + fan-in combine. No row-max
// (|s|<=~13, fp32-safe, softmax shift-invariant). Per 32q x 32k tile:
//   S^T = mfma_32x32x16(A=K, B=Q): lane owns q=lane&31, k=(r&3)+8*(r>>2)+4h.
//   p = exp2(S); v_perm bf16 pack; v_permlane32_swap -> PV A-frags.
//   O += mfma_32x32x16(A=P, B=V) x2. V ones-column gives l for free.
// After storing partials, last block of each qc (atomic counter) combines
// all SPLIT partials and writes the normalized output (deterministic: fixed
// summation order, single combiner; release/acquire via __threadfence()).
// ---------------------------------------------------------------------------
__global__ __launch_bounds__(256) void attn_kernel(char* __restrict__ ws,
                                                   float* __restrict__ out) {
  __shared__ uint4 sK[2 * KB];   // 16 KB: K planes [2][KB]
  __shared__ uint4 sVT[KB * 2];  // 16 KB: V^T interleaved units
  __shared__ int isLast;

  const int tid = threadIdx.x;
  const int lane = tid & 63;
  const int wv = tid >> 6;
  const int h = lane >> 5;
  const int l31 = lane & 31;
  const int qc = blockIdx.x >> 4;  // SPLIT=16
  const int kc = blockIdx.x & 15;
  const int kt0 = kc * KB;
  const int q0 = qc * QBLK + wv * 32;

  const uint4* gK = (const uint4*)(ws + KB_OFF);
  const uint4* gV = (const uint4*)(ws + VT_OFF) + kt0 * 2;
  float* part = (float*)(ws + PART_OFF);

  // async global->LDS staging, 16B/lane, wave-linear dest
#pragma unroll
  for (int c = 0; c < 2; ++c) {
#pragma unroll
    for (int i = 0; i < 2; ++i) {
      int o = wv * 64 + 256 * i;
      __builtin_amdgcn_global_load_lds(
          (const __attribute__((address_space(1))) void*)(gK + c * NROWS + kt0 + o + lane),
          (__attribute__((address_space(3))) void*)(sK + c * KB + o), 16, 0, 0);
    }
  }
#pragma unroll
  for (int i = 0; i < 4; ++i) {
    int o = wv * 64 + 256 * i;
    __builtin_amdgcn_global_load_lds(
        (const __attribute__((address_space(1))) void*)(gV + o + lane),
        (__attribute__((address_space(3))) void*)(sVT + o), 16, 0, 0);
  }

  // Q fragment: lane holds Q[q0 + (lane&31)][ch 8h..8h+7]
  const char* Qb = ws + QB_OFF;
  short8 qf = *(const short8*)(Qb + (q0 + l31) * 32 + h * 16);

  f32x16 oacc, zf;
#pragma unroll
  for (int r = 0; r < 16; ++r) { oacc[r] = 0.f; zf[r] = 0.f; }

  __syncthreads();

  for (int it = 0; it < KB / 32; ++it) {
    // K fragment: plane h, rows it*32 + l31 -> contiguous 16B/lane
    short8 kf = *(const short8*)((const char*)sK + h * (KB * 16) +
                                 (it * 32 + l31) * 16);
    f32x16 s = __builtin_amdgcn_mfma_f32_32x32x16_bf16(kf, qf, zf, 0, 0, 0);

    float p[16];
#pragma unroll
    for (int r = 0; r < 16; ++r) p[r] = __builtin_amdgcn_exp2f(s[r]);

#define PK(a, b) __builtin_amdgcn_perm(__float_as_uint(b), __float_as_uint(a), 0x07060302u)
    unsigned P01 = PK(p[0], p[1]), P23 = PK(p[2], p[3]);
    unsigned P45 = PK(p[4], p[5]), P67 = PK(p[6], p[7]);
    unsigned P89 = PK(p[8], p[9]), Pab = PK(p[10], p[11]);
    unsigned Pcd = PK(p[12], p[13]), Pef = PK(p[14], p[15]);
#undef PK
    SWAP32(P01, P45);
    SWAP32(P23, P67);
    SWAP32(P89, Pcd);
    SWAP32(Pab, Pef);
    uvec4 c0 = {P01, P23, P45, P67};  // k 0..15: word j = P[q][k=8h+2j..+2j+1]
    uvec4 c1 = {P89, Pab, Pcd, Pef};  // k 16..31
    short8 a0 = __builtin_bit_cast(short8, c0);
    short8 a1 = __builtin_bit_cast(short8, c1);

    // V fragments: lane holds V[k=16c+8h+i][d=lane&15]
    const char* vb = (const char*)sVT;
    short8 v0 = *(const short8*)(vb + (it * 4 + h) * 256 + (lane & 15) * 16);
    short8 v1 = *(const short8*)(vb + (it * 4 + 2 + h) * 256 + (lane & 15) * 16);

    oacc = __builtin_amdgcn_mfma_f32_32x32x16_bf16(a0, v0, oacc, 0, 0, 0);
    oacc = __builtin_amdgcn_mfma_f32_32x32x16_bf16(a1, v1, oacc, 0, 0, 0);
  }

  // partial store; d = lane&31 < 12, q unique per (r,h)
  if (l31 < 12) {
#pragma unroll
    for (int r = 0; r < 16; ++r) {
      int q = (r & 3) + 8 * (r >> 2) + 4 * h;
      part[((size_t)kc * NROWS + q0 + q) * 12 + l31] = oacc[r];
    }
  }

  // ---- fan-in: last block of this qc combines + normalizes ----
  __threadfence();   // release: flush partial stores agent-wide
  __syncthreads();
  if (tid == 0) {
    int* cnt = (int*)(ws + CNT_OFF);
    int old = atomicAdd(&cnt[qc], 1);
    isLast = (old == SPLIT - 1);
  }
  __syncthreads();
  if (!isLast) return;

  __threadfence();   // acquire: invalidate caches, see all XCDs' partials
  if (tid < QBLK) {
    int row = qc * QBLK + tid;
    const float4* p4 = (const float4*)part;
    float r[12];
#pragma unroll
    for (int d = 0; d < 12; ++d) r[d] = 0.f;
#pragma unroll
    for (int k = 0; k < SPLIT; ++k) {
      size_t b = ((size_t)k * NROWS + row) * 3;
      float4 t0 = p4[b], t1 = p4[b + 1], t2 = p4[b + 2];
      r[0] += t0.x; r[1] += t0.y; r[2] += t0.z; r[3] += t0.w;
      r[4] += t1.x; r[5] += t1.y; r[6] += t1.z; r[7] += t1.w;
      r[8] += t2.x; r[9] += t2.y; r[10] += t2.z; r[11] += t2.w;
    }
    float inv = 1.0f / r[11];
    float* o = out + (size_t)row * OUTCH;
#pragma unroll
    for (int d = 0; d < OUTCH; ++d) o[d] = r[d] * inv;
  }
}

extern "C" void kernel_launch(void* const* d_in, const int* in_sizes, int n_in,
                              void* d_out, int out_size, void* d_ws, size_t ws_size,
                              hipStream_t stream) {
  const float* x = (const float*)d_in[0];
  const float* gamma = (const float*)d_in[1];
  const float* beta = (const float*)d_in[2];
  const float* W = (const float*)d_in[3];
  char* ws = (char*)d_ws;  // needs ~7.1 MB (planes + partials + counters)
  float* out = (float*)d_out;

  qkv_ln_kernel<<<NROWS / 64, 64, 0, stream>>>(x, gamma, beta, W, ws);
  attn_kernel<<<(NROWS / QBLK) * SPLIT, 256, 0, stream>>>(ws, out);
}

// Round 8
// 31.894 us; speedup vs baseline: 5.9650x; 5.9650x over previous
//
#include <hip/hip_runtime.h>

#define NROWS 8192
#define INCH 10
#define NQKV 33
#define OUTCH 11
#define SPLIT 16
#define KB 512            // k-rows per block (LDS-resident, computed in-block)
#define QBLK 128          // q-rows per block (4 waves x 32)

typedef short short8 __attribute__((ext_vector_type(8)));
typedef float f32x16 __attribute__((ext_vector_type(16)));
typedef unsigned int uvec4 __attribute__((ext_vector_type(4)));

// ws layout: f32 part[SPLIT][NROWS][12] partials (o0..o10, l) only.
// Q/K/V never touch global memory: each block recomputes LN+Linear for the
// 128 Q rows + 512 K/V rows it needs, directly into LDS (~0.3 us/block of
// VALU; 64x redundancy is far cheaper than a kernel-launch boundary).

// v_permlane32_swap_b32 a, b:
//   a' = {a.lo32lanes, b.lo32lanes}, b' = {a.hi32lanes, b.hi32lanes}
#define SWAP32(a, b) asm("v_permlane32_swap_b32 %0, %1" : "+v"(a), "+v"(b))

__device__ inline unsigned short f2bf(float f) {
  unsigned u = __float_as_uint(f);
  unsigned r = (u + 0x7FFFu + ((u >> 16) & 1u)) >> 16;  // RNE
  return (unsigned short)r;
}

// ---------------------------------------------------------------------------
// Kernel 1: fused LN+Linear+flash-attention partials.
// Phase A: block computes bf16 Q rows (its qc chunk) and K planes + V^T
//   (its kc chunk) straight into LDS. Only the needed Linear outputs are
//   computed (Q rows: oc 0..10; K/V rows: oc 11..32).
// Phase B: r4's proven inner loop. No row-max (|s|<=~13, fp32-safe,
//   softmax shift-invariant). Per 32q x 32k tile:
//   S^T = mfma_32x32x16(A=K, B=Q); p = exp2(S); v_perm bf16 pack;
//   permlane32_swap -> PV A-frags; O += mfma(P, V) x2; V ones-column
//   yields the softmax denominator for free.
// Epilogue: plain per-(qc,kc) partial stores. No fences, no atomics.
// ---------------------------------------------------------------------------
__global__ __launch_bounds__(256) void fused_attn_kernel(
    const float* __restrict__ x, const float* __restrict__ gamma,
    const float* __restrict__ beta, const float* __restrict__ W,
    float* __restrict__ part) {
  __shared__ uint4 sK[2 * KB];            // 16 KB: K planes [2][KB][16B]
  __shared__ uint4 sVT[(KB / 8) * 16];    // 16 KB: V^T units [(k>>3)*16+d][8]
  __shared__ uint4 sQ[QBLK * 2];          // 4 KB:  Q rows [128][32B]
  __shared__ float sW[NQKV * INCH];
  __shared__ float sg[INCH];
  __shared__ float sb[INCH];

  const int tid = threadIdx.x;
  const int lane = tid & 63;
  const int wv = tid >> 6;
  const int h = lane >> 5;
  const int l31 = lane & 31;
  const int qc = blockIdx.x >> 4;  // SPLIT=16
  const int kc = blockIdx.x & 15;
  const int kt0 = kc * KB;
  const int q0blk = qc * QBLK;
  const int q0 = q0blk + wv * 32;

  for (int i = tid; i < NQKV * INCH; i += 256) sW[i] = W[i];
  if (tid < INCH) { sg[tid] = gamma[tid]; sb[tid] = beta[tid]; }
  __syncthreads();

  // ---- Phase A: LN + Linear into LDS ----
  const float2* x2 = (const float2*)x;  // rows are 40B = 5 float2, 8B aligned
  const float QSC = 0.31622776601683794f * 1.4426950408889634f;  // scale*log2e

#define LNROW(row, hh)                                                     \
  {                                                                        \
    float xv[INCH];                                                        \
    _Pragma("unroll") for (int j = 0; j < 5; ++j) {                        \
      float2 t = x2[(row) * 5 + j];                                        \
      xv[2 * j] = t.x;                                                     \
      xv[2 * j + 1] = t.y;                                                 \
    }                                                                      \
    float mu = 0.f;                                                        \
    _Pragma("unroll") for (int i = 0; i < INCH; ++i) mu += xv[i];          \
    mu *= (1.0f / INCH);                                                   \
    float var = 0.f;                                                       \
    _Pragma("unroll") for (int i = 0; i < INCH; ++i) {                     \
      float d = xv[i] - mu;                                                \
      var += d * d;                                                        \
    }                                                                      \
    var *= (1.0f / INCH);                                                  \
    float rstd = rsqrtf(var + 1e-5f);                                      \
    _Pragma("unroll") for (int i = 0; i < INCH; ++i)                       \
        hh[i] = (xv[i] - mu) * rstd * sg[i] + sb[i];                       \
  }

  // K/V rows: 2 per thread (r = tid, tid+256)
#pragma unroll
  for (int i = 0; i < 2; ++i) {
    int r = tid + 256 * i;       // local k row in [0, KB)
    int row = kt0 + r;
    float hv[INCH];
    LNROW(row, hv)
    float acc[NQKV - OUTCH];     // oc 11..32: K then V
#pragma unroll
    for (int oc = 0; oc < NQKV - OUTCH; ++oc) {
      float s = 0.f;
#pragma unroll
      for (int j = 0; j < INCH; ++j) s += hv[j] * sW[(OUTCH + oc) * INCH + j];
      acc[oc] = s;
    }
    // K planes
    unsigned short e[16];
#pragma unroll
    for (int j = 0; j < 16; ++j) e[j] = (j < OUTCH) ? f2bf(acc[j]) : 0;
    unsigned qw[8];
#pragma unroll
    for (int j = 0; j < 8; ++j)
      qw[j] = (unsigned)e[2 * j] | ((unsigned)e[2 * j + 1] << 16);
    sK[r] = uint4{qw[0], qw[1], qw[2], qw[3]};        // plane 0 (ch 0..7)
    sK[KB + r] = uint4{qw[4], qw[5], qw[6], qw[7]};   // plane 1 (ch 8..15)
    // V^T scatter
    unsigned short* vtu = (unsigned short*)sVT;
    int u0 = (r >> 3) * 16;
    int slot = r & 7;
#pragma unroll
    for (int d = 0; d < 16; ++d) {
      unsigned short v;
      if (d < OUTCH)       v = f2bf(acc[OUTCH + d]);
      else if (d == OUTCH) v = 0x3F80;  // ones column -> softmax denominator
      else                 v = 0;
      vtu[(u0 + d) * 8 + slot] = v;
    }
  }
  // Q rows: 1 per thread for tid < 128 (only oc 0..10 needed)
  if (tid < QBLK) {
    int row = q0blk + tid;
    float hv[INCH];
    LNROW(row, hv)
    unsigned short e[16];
#pragma unroll
    for (int oc = 0; oc < 16; ++oc) {
      float s = 0.f;
      if (oc < OUTCH) {
#pragma unroll
        for (int j = 0; j < INCH; ++j) s += hv[j] * sW[oc * INCH + j];
      }
      e[oc] = (oc < OUTCH) ? f2bf(s * QSC) : 0;
    }
    unsigned qw[8];
#pragma unroll
    for (int j = 0; j < 8; ++j)
      qw[j] = (unsigned)e[2 * j] | ((unsigned)e[2 * j + 1] << 16);
    sQ[tid * 2 + 0] = uint4{qw[0], qw[1], qw[2], qw[3]};
    sQ[tid * 2 + 1] = uint4{qw[4], qw[5], qw[6], qw[7]};
  }
#undef LNROW

  __syncthreads();

  // ---- Phase B: attention ----
  // Q fragment: lane holds Q[q0 + (lane&31)][ch 8h..8h+7]
  short8 qf = *(const short8*)((const char*)sQ + (wv * 32 + l31) * 32 + h * 16);

  f32x16 oacc, zf;
#pragma unroll
  for (int r = 0; r < 16; ++r) { oacc[r] = 0.f; zf[r] = 0.f; }

  for (int it = 0; it < KB / 32; ++it) {
    // K fragment: plane h, rows it*32 + l31 -> contiguous 16B/lane
    short8 kf = *(const short8*)((const char*)sK + h * (KB * 16) +
                                 (it * 32 + l31) * 16);
    f32x16 s = __builtin_amdgcn_mfma_f32_32x32x16_bf16(kf, qf, zf, 0, 0, 0);

    float p[16];
#pragma unroll
    for (int r = 0; r < 16; ++r) p[r] = __builtin_amdgcn_exp2f(s[r]);

#define PK(a, b) __builtin_amdgcn_perm(__float_as_uint(b), __float_as_uint(a), 0x07060302u)
    unsigned P01 = PK(p[0], p[1]), P23 = PK(p[2], p[3]);
    unsigned P45 = PK(p[4], p[5]), P67 = PK(p[6], p[7]);
    unsigned P89 = PK(p[8], p[9]), Pab = PK(p[10], p[11]);
    unsigned Pcd = PK(p[12], p[13]), Pef = PK(p[14], p[15]);
#undef PK
    SWAP32(P01, P45);
    SWAP32(P23, P67);
    SWAP32(P89, Pcd);
    SWAP32(Pab, Pef);
    uvec4 c0 = {P01, P23, P45, P67};  // k 0..15: word j = P[q][k=8h+2j..+2j+1]
    uvec4 c1 = {P89, Pab, Pcd, Pef};  // k 16..31
    short8 a0 = __builtin_bit_cast(short8, c0);
    short8 a1 = __builtin_bit_cast(short8, c1);

    // V fragments: lane holds V[k=16c+8h+i][d=lane&15]
    const char* vb = (const char*)sVT;
    short8 v0 = *(const short8*)(vb + (it * 4 + h) * 256 + (lane & 15) * 16);
    short8 v1 = *(const short8*)(vb + (it * 4 + 2 + h) * 256 + (lane & 15) * 16);

    oacc = __builtin_amdgcn_mfma_f32_32x32x16_bf16(a0, v0, oacc, 0, 0, 0);
    oacc = __builtin_amdgcn_mfma_f32_32x32x16_bf16(a1, v1, oacc, 0, 0, 0);
  }

  // per-(q,d) partial store; d = lane&31 < 12, q unique per (r,h)
  if (l31 < 12) {
#pragma unroll
    for (int r = 0; r < 16; ++r) {
      int q = (r & 3) + 8 * (r >> 2) + 4 * h;
      part[((size_t)kc * NROWS + q0 + q) * 12 + l31] = oacc[r];
    }
  }
}

// ---------------------------------------------------------------------------
// Kernel 2: combine SPLIT partials and normalize.
// ---------------------------------------------------------------------------
__global__ __launch_bounds__(64) void norm_kernel(const float* __restrict__ part,
                                                  float* __restrict__ out) {
  int row = blockIdx.x * 64 + threadIdx.x;
  const float4* p4 = (const float4*)part;
  float r[12];
#pragma unroll
  for (int d = 0; d < 12; ++d) r[d] = 0.f;
#pragma unroll
  for (int kc = 0; kc < SPLIT; ++kc) {
    size_t b = ((size_t)kc * NROWS + row) * 3;
    float4 t0 = p4[b], t1 = p4[b + 1], t2 = p4[b + 2];
    r[0] += t0.x; r[1] += t0.y; r[2] += t0.z; r[3] += t0.w;
    r[4] += t1.x; r[5] += t1.y; r[6] += t1.z; r[7] += t1.w;
    r[8] += t2.x; r[9] += t2.y; r[10] += t2.z; r[11] += t2.w;
  }
  float inv = 1.0f / r[11];
  float* o = out + (size_t)row * OUTCH;
#pragma unroll
  for (int d = 0; d < OUTCH; ++d) o[d] = r[d] * inv;
}

extern "C" void kernel_launch(void* const* d_in, const int* in_sizes, int n_in,
                              void* d_out, int out_size, void* d_ws, size_t ws_size,
                              hipStream_t stream) {
  const float* x = (const float*)d_in[0];
  const float* gamma = (const float*)d_in[1];
  const float* beta = (const float*)d_in[2];
  const float* W = (const float*)d_in[3];
  float* part = (float*)d_ws;  // SPLIT*NROWS*12*4 = 6.3 MB
  float* out = (float*)d_out;

  fused_attn_kernel<<<(NROWS / QBLK) * SPLIT, 256, 0, stream>>>(
      x, gamma, beta, W, part);
  norm_kernel<<<NROWS / 64, 64, 0, stream>>>(part, out);
}

// Round 9
// 22.563 us; speedup vs baseline: 8.4317x; 1.4135x over previous
//
#include <hip/hip_runtime.h>

#define NROWS 8192
#define INCH 10
#define NQKV 33
#define OUTCH 11
#define QBLK 32           // q-rows per block; all 8 waves share them
#define KWAVE 1024        // k-rows per wave (8 waves cover all 8192)
#define KTILE 128         // k-rows per staged tile (double-buffered per wave)

typedef short short8 __attribute__((ext_vector_type(8)));
typedef float f32x16 __attribute__((ext_vector_type(16)));
typedef unsigned int uvec4 __attribute__((ext_vector_type(4)));

// ws byte layout (Q/K/V planes only; no partials needed anymore):
//   QB_OFF: Q bf16 [NROWS][16ch] rows of 32B (scale*log2e folded into q)
//   KB_OFF: K bf16 planes [2][NROWS][16B]: plane c holds ch 8c..8c+7
//   VT_OFF: V^T bf16 interleaved: 16B unit u=(k>>3)*16+d holds V[(k&~7)+slot][d],
//           d=0..10 v, d=11 ones (softmax denom), d=12..15 zero
#define QB_OFF   0
#define KB_OFF   (NROWS * 32)
#define VT_OFF   (2 * NROWS * 32)

#define AS1 __attribute__((address_space(1)))
#define AS3 __attribute__((address_space(3)))

// v_permlane32_swap_b32 a, b:
//   a' = {a.lo32lanes, b.lo32lanes}, b' = {a.hi32lanes, b.hi32lanes}
#define SWAP32(a, b) asm("v_permlane32_swap_b32 %0, %1" : "+v"(a), "+v"(b))

__device__ inline unsigned short f2bf(float f) {
  unsigned u = __float_as_uint(f);
  unsigned r = (u + 0x7FFFu + ((u >> 16) & 1u)) >> 16;  // RNE
  return (unsigned short)r;
}

// ---------------------------------------------------------------------------
// Kernel A (r4-proven, unchanged): LayerNorm + Linear(10->33);
// emit bf16 Q rows, K planes, V^T.
// ---------------------------------------------------------------------------
__global__ __launch_bounds__(64) void qkv_ln_kernel(
    const float* __restrict__ x, const float* __restrict__ gamma,
    const float* __restrict__ beta, const float* __restrict__ W,
    char* __restrict__ ws) {
  __shared__ float sW[NQKV * INCH];
  __shared__ float sg[INCH];
  __shared__ float sb[INCH];
  int tid = threadIdx.x;
  for (int i = tid; i < NQKV * INCH; i += 64) sW[i] = W[i];
  if (tid < INCH) { sg[tid] = gamma[tid]; sb[tid] = beta[tid]; }
  __syncthreads();

  int row = blockIdx.x * 64 + tid;
  const float2* x2 = (const float2*)x;  // rows are 40B = 5 float2, 8B aligned
  float xv[INCH];
#pragma unroll
  for (int j = 0; j < 5; ++j) {
    float2 t = x2[row * 5 + j];
    xv[2 * j] = t.x;
    xv[2 * j + 1] = t.y;
  }

  float mu = 0.f;
#pragma unroll
  for (int i = 0; i < INCH; ++i) mu += xv[i];
  mu *= (1.0f / INCH);
  float var = 0.f;
#pragma unroll
  for (int i = 0; i < INCH; ++i) { float d = xv[i] - mu; var += d * d; }
  var *= (1.0f / INCH);
  float rstd = rsqrtf(var + 1e-5f);
  float h[INCH];
#pragma unroll
  for (int i = 0; i < INCH; ++i) h[i] = (xv[i] - mu) * rstd * sg[i] + sb[i];

  float acc[NQKV];
#pragma unroll
  for (int oc = 0; oc < NQKV; ++oc) {
    float s = 0.f;
#pragma unroll
    for (int i = 0; i < INCH; ++i) s += h[i] * sW[oc * INCH + i];
    acc[oc] = s;
  }

  // exp(s*scale) = exp2(s*scale*log2e): fold into q.
  const float QSC = 0.31622776601683794f * 1.4426950408889634f;

  unsigned short e[16];
  unsigned qw[8];
  // ---- Q row ----
#pragma unroll
  for (int i = 0; i < 16; ++i) e[i] = (i < OUTCH) ? f2bf(acc[i] * QSC) : 0;
#pragma unroll
  for (int i = 0; i < 8; ++i)
    qw[i] = (unsigned)e[2 * i] | ((unsigned)e[2 * i + 1] << 16);
  uint4* Qb = (uint4*)(ws + QB_OFF);
  Qb[row * 2 + 0] = make_uint4(qw[0], qw[1], qw[2], qw[3]);
  Qb[row * 2 + 1] = make_uint4(qw[4], qw[5], qw[6], qw[7]);
  // ---- K planes ----
#pragma unroll
  for (int i = 0; i < 16; ++i) e[i] = (i < OUTCH) ? f2bf(acc[OUTCH + i]) : 0;
#pragma unroll
  for (int i = 0; i < 8; ++i)
    qw[i] = (unsigned)e[2 * i] | ((unsigned)e[2 * i + 1] << 16);
  uint4* Kb = (uint4*)(ws + KB_OFF);
  Kb[row] = make_uint4(qw[0], qw[1], qw[2], qw[3]);          // plane 0
  Kb[NROWS + row] = make_uint4(qw[4], qw[5], qw[6], qw[7]);  // plane 1
  // ---- V^T scatter (2B stores into interleaved units) ----
  unsigned short* VTu = (unsigned short*)(ws + VT_OFF);
  int u0 = (row >> 3) * 16;
  int slot = row & 7;
#pragma unroll
  for (int d = 0; d < 16; ++d) {
    unsigned short v;
    if (d < OUTCH)       v = f2bf(acc[2 * OUTCH + d]);
    else if (d == OUTCH) v = 0x3F80;  // ones column -> softmax denominator
    else                 v = 0;
    VTu[(u0 + d) * 8 + slot] = v;
  }
}

// ---------------------------------------------------------------------------
// Kernel B: full-K flash attention with IN-BLOCK k-split (no partial
// round-trip, no kernel C, no fences). 256 blocks x 512 thr (8 waves).
// All waves share the block's 32 q-rows; wave w streams k-chunk
// [w*1024, w*1024+1024) through its PRIVATE double-buffered LDS region
// (no barriers in the main loop). Counted s_waitcnt vmcnt(8) keeps the
// next tile's 8 global_load_lds in flight across compute (T4 idiom).
// Inner tile = r4's proven pipeline: S^T = mfma(K,Q); p = exp2(S);
// v_perm bf16 pack; permlane32_swap -> PV A-frags; O += mfma(P,V) x2;
// V ones-column yields the denominator. No row-max (|s|<=~13, fp32-safe).
// Epilogue: one __syncthreads, sum 8 wave-partials from LDS, normalize.
// ---------------------------------------------------------------------------
__global__ __launch_bounds__(512) void attn_kernel(const char* __restrict__ ws,
                                                   float* __restrict__ out) {
  __shared__ uint4 sStage[8 * 1024];        // 128 KB: per-wave [2][512] uint4
  __shared__ float sPart[8 * QBLK * 16];    // 16 KB: per-wave (o,l) tiles

  const int tid = threadIdx.x;
  const int lane = tid & 63;
  const int w = tid >> 6;       // wave id = k-chunk id
  const int h = lane >> 5;
  const int l31 = lane & 31;
  const int q0 = blockIdx.x * QBLK;
  const int kbase = w * KWAVE;

  const uint4* gK = (const uint4*)(ws + KB_OFF);  // [2][NROWS] 16B units
  const uint4* gV = (const uint4*)(ws + VT_OFF);  // [NROWS*2]  16B units

  uint4* myStage = sStage + w * 1024;  // 16 KB private: two 8KB buffers

  // stage tile t (128 k-rows) into buffer b: [0,256)=K planes, [256,512)=V^T
#define STAGE(b, k0)                                                         \
  {                                                                          \
    uint4* buf = myStage + (b) * 512;                                        \
    _Pragma("unroll") for (int c = 0; c < 2; ++c) {                          \
      _Pragma("unroll") for (int i = 0; i < 2; ++i) {                        \
        __builtin_amdgcn_global_load_lds(                                    \
            (const AS1 void*)(gK + c * NROWS + (k0) + i * 64 + lane),        \
            (AS3 void*)(buf + c * 128 + i * 64), 16, 0, 0);                  \
      }                                                                      \
    }                                                                        \
    _Pragma("unroll") for (int i = 0; i < 4; ++i) {                          \
      __builtin_amdgcn_global_load_lds(                                      \
          (const AS1 void*)(gV + (k0) * 2 + i * 64 + lane),                  \
          (AS3 void*)(buf + 256 + i * 64), 16, 0, 0);                        \
    }                                                                        \
  }

  STAGE(0, kbase)

  // Q fragment straight from global (L2-hot): Q[q0+(lane&31)][ch 8h..8h+7]
  short8 qf = *(const short8*)(ws + QB_OFF + (q0 + l31) * 32 + h * 16);

  f32x16 oacc, zf;
#pragma unroll
  for (int r = 0; r < 16; ++r) { oacc[r] = 0.f; zf[r] = 0.f; }

  for (int t = 0; t < KWAVE / KTILE; ++t) {  // 8 tiles
    if (t < KWAVE / KTILE - 1) {
      STAGE((t + 1) & 1, kbase + (t + 1) * KTILE)
      asm volatile("s_waitcnt vmcnt(8)" ::: "memory");
    } else {
      asm volatile("s_waitcnt vmcnt(0)" ::: "memory");
    }
    __builtin_amdgcn_sched_barrier(0);

    const char* buf = (const char*)(myStage + (t & 1) * 512);
    const char* vb = buf + 4096;
#pragma unroll
    for (int it = 0; it < KTILE / 32; ++it) {
      // K fragment: plane h, rows it*32 + l31 -> contiguous 16B/lane
      short8 kf = *(const short8*)(buf + h * 2048 + (it * 32 + l31) * 16);
      f32x16 s = __builtin_amdgcn_mfma_f32_32x32x16_bf16(kf, qf, zf, 0, 0, 0);

      float p[16];
#pragma unroll
      for (int r = 0; r < 16; ++r) p[r] = __builtin_amdgcn_exp2f(s[r]);

#define PK(a, b) __builtin_amdgcn_perm(__float_as_uint(b), __float_as_uint(a), 0x07060302u)
      unsigned P01 = PK(p[0], p[1]), P23 = PK(p[2], p[3]);
      unsigned P45 = PK(p[4], p[5]), P67 = PK(p[6], p[7]);
      unsigned P89 = PK(p[8], p[9]), Pab = PK(p[10], p[11]);
      unsigned Pcd = PK(p[12], p[13]), Pef = PK(p[14], p[15]);
#undef PK
      SWAP32(P01, P45);
      SWAP32(P23, P67);
      SWAP32(P89, Pcd);
      SWAP32(Pab, Pef);
      uvec4 c0 = {P01, P23, P45, P67};  // k 0..15: word j = P[q][k=8h+2j..]
      uvec4 c1 = {P89, Pab, Pcd, Pef};  // k 16..31
      short8 a0 = __builtin_bit_cast(short8, c0);
      short8 a1 = __builtin_bit_cast(short8, c1);

      // V fragments: lane holds V[k=16c'+8h+i][d=lane&15]
      short8 v0 = *(const short8*)(vb + (it * 4 + h) * 256 + (lane & 15) * 16);
      short8 v1 = *(const short8*)(vb + (it * 4 + 2 + h) * 256 + (lane & 15) * 16);

      oacc = __builtin_amdgcn_mfma_f32_32x32x16_bf16(a0, v0, oacc, 0, 0, 0);
      oacc = __builtin_amdgcn_mfma_f32_32x32x16_bf16(a1, v1, oacc, 0, 0, 0);
    }
  }
#undef STAGE

  // wave-partials -> LDS; d = lane&31 < 12, q unique per (r,h)
  if (l31 < 12) {
#pragma unroll
    for (int r = 0; r < 16; ++r) {
      int q = (r & 3) + 8 * (r >> 2) + 4 * h;
      sPart[(w * QBLK + q) * 16 + l31] = oacc[r];
    }
  }
  __syncthreads();

  // in-block combine + normalize: thread (q = tid>>4, c = tid&15)
  {
    int q = tid >> 4;
    int c = tid & 15;
    if (c < OUTCH) {
      float o = 0.f, l = 0.f;
#pragma unroll
      for (int wv = 0; wv < 8; ++wv) {
        o += sPart[(wv * QBLK + q) * 16 + c];
        l += sPart[(wv * QBLK + q) * 16 + 11];
      }
      out[(size_t)(q0 + q) * OUTCH + c] = o / l;
    }
  }
}

extern "C" void kernel_launch(void* const* d_in, const int* in_sizes, int n_in,
                              void* d_out, int out_size, void* d_ws, size_t ws_size,
                              hipStream_t stream) {
  const float* x = (const float*)d_in[0];
  const float* gamma = (const float*)d_in[1];
  const float* beta = (const float*)d_in[2];
  const float* W = (const float*)d_in[3];
  char* ws = (char*)d_ws;  // 768 KB of Q/K/V planes
  float* out = (float*)d_out;

  qkv_ln_kernel<<<NROWS / 64, 64, 0, stream>>>(x, gamma, beta, W, ws);
  attn_kernel<<<NROWS / QBLK, 512, 0, stream>>>(ws, out);
}